// Round 1
// baseline (3593.887 us; speedup 1.0000x reference)
//
#include <hip/hip_runtime.h>
#include <math.h>

#define DT    0.01f
#define B_    64
#define S_    4096
#define I_    128
#define H_    256
#define O_    128

// ---------------------------------------------------------------------------
// Kernel 1: xproj[b,t,j] = b[j] + sum_i x[b,t,i] * W[i,j]   (W rows 0..127)
// Tile: each block = 64 rows (b,t pairs), 256 threads = one output column j
// each. W column (128 f32) held in registers; x rows staged in LDS and read
// as uniform-address broadcasts.
// ---------------------------------------------------------------------------
#define RPB 64

__global__ __launch_bounds__(256, 2) void xproj_kernel(
    const float* __restrict__ x, const float* __restrict__ W,
    const float* __restrict__ bias, float* __restrict__ xp)
{
  __shared__ __align__(16) float xs[RPB][I_];
  const int j = threadIdx.x;

  float w[I_];
#pragma unroll
  for (int k = 0; k < I_; ++k) w[k] = W[k * H_ + j];
  const float bj = bias[j];

  const size_t row0 = (size_t)blockIdx.x * RPB;

  // cooperative stage of RPB x-rows: RPB*I_/4 = 2048 float4, 8 per thread
  const float4* src4 = (const float4*)(x + row0 * I_);
  float4* xs4 = (float4*)&xs[0][0];
#pragma unroll
  for (int i = 0; i < (RPB * I_ / 4) / 256; ++i)
    xs4[j + i * 256] = src4[j + i * 256];
  __syncthreads();

  for (int r = 0; r < RPB; r += 4) {
    float a0 = bj, a1 = bj, a2 = bj, a3 = bj;
    const float4* r0 = (const float4*)xs[r + 0];
    const float4* r1 = (const float4*)xs[r + 1];
    const float4* r2 = (const float4*)xs[r + 2];
    const float4* r3 = (const float4*)xs[r + 3];
#pragma unroll
    for (int k4 = 0; k4 < I_ / 4; ++k4) {
      float4 v0 = r0[k4], v1 = r1[k4], v2 = r2[k4], v3 = r3[k4];
      a0 = fmaf(v0.x, w[4*k4+0], a0); a0 = fmaf(v0.y, w[4*k4+1], a0);
      a0 = fmaf(v0.z, w[4*k4+2], a0); a0 = fmaf(v0.w, w[4*k4+3], a0);
      a1 = fmaf(v1.x, w[4*k4+0], a1); a1 = fmaf(v1.y, w[4*k4+1], a1);
      a1 = fmaf(v1.z, w[4*k4+2], a1); a1 = fmaf(v1.w, w[4*k4+3], a1);
      a2 = fmaf(v2.x, w[4*k4+0], a2); a2 = fmaf(v2.y, w[4*k4+1], a2);
      a2 = fmaf(v2.z, w[4*k4+2], a2); a2 = fmaf(v2.w, w[4*k4+3], a2);
      a3 = fmaf(v3.x, w[4*k4+0], a3); a3 = fmaf(v3.y, w[4*k4+1], a3);
      a3 = fmaf(v3.z, w[4*k4+2], a3); a3 = fmaf(v3.w, w[4*k4+3], a3);
    }
    xp[(row0 + r + 0) * H_ + j] = a0;
    xp[(row0 + r + 1) * H_ + j] = a1;
    xp[(row0 + r + 2) * H_ + j] = a2;
    xp[(row0 + r + 3) * H_ + j] = a3;
  }
}

// ---------------------------------------------------------------------------
// Kernel 2 (main path): sequential LTC recurrence, one block per batch elem.
// 1024 threads: thread (j = t&255, c = t>>8) holds W_h[c*64+kk][j] in regs.
// Per step: 4-way K-split partial dot, LDS reduce, c==0 does tanh + ODE
// update. xproj prefetched one step ahead. Final h @ Wo + bo fused at end.
// ---------------------------------------------------------------------------
__global__ __launch_bounds__(1024) void ltc_main(
    const float* __restrict__ xp, const float* __restrict__ W,
    const float* __restrict__ tau, const float* __restrict__ A,
    const float* __restrict__ Wo, const float* __restrict__ bo,
    float* __restrict__ out)
{
  const int b = blockIdx.x;
  const int t = threadIdx.x;
  const int j = t & (H_ - 1);
  const int c = t >> 8;  // 0..3, wave-uniform

  float w[64];
#pragma unroll
  for (int kk = 0; kk < 64; ++kk)
    w[kk] = W[(I_ + c * 64 + kk) * H_ + j];

  __shared__ __align__(16) float hs[H_];
  __shared__ float ps[3][H_];

  float Aj = 0.f, itau = 0.f, xpre = 0.f;
  const float* xprow = xp + (size_t)b * S_ * H_;
  if (c == 0) {
    Aj = A[j];
    itau = 1.0f / tau[j];
    xpre = xprow[j];  // step 0
    hs[j] = 0.0f;
  }
  __syncthreads();

  for (int step = 0; step < S_; ++step) {
    // prefetch next step's x-projection (issued early, consumed after barrier)
    float xnext = 0.f;
    if (c == 0) {
      const int snext = (step + 1 < S_) ? step + 1 : step;
      xnext = xprow[(size_t)snext * H_ + j];
    }

    // partial dot: this thread's 64-element K-chunk (LDS broadcast reads)
    float acc = 0.0f;
#pragma unroll
    for (int kk = 0; kk < 64; kk += 4) {
      float4 h4 = *(const float4*)&hs[c * 64 + kk];
      acc = fmaf(h4.x, w[kk + 0], acc);
      acc = fmaf(h4.y, w[kk + 1], acc);
      acc = fmaf(h4.z, w[kk + 2], acc);
      acc = fmaf(h4.w, w[kk + 3], acc);
    }

    if (c) ps[c - 1][j] = acc;
    __syncthreads();

    if (c == 0) {
      const float z = acc + ps[0][j] + ps[1][j] + ps[2][j] + xpre;
      const float f = tanhf(z);
      const float hj = hs[j];
      hs[j] = (hj + DT * f * Aj) / (1.0f + DT * (itau + f));
      xpre = xnext;
    }
    __syncthreads();
  }

  // fused output projection: out[b,o] = bo[o] + sum_h hs[h] * Wo[h,o]
  if (t < O_) {
    float acc = bo[t];
#pragma unroll 8
    for (int h = 0; h < H_; ++h)
      acc = fmaf(hs[h], Wo[h * O_ + t], acc);
    out[b * O_ + t] = acc;
  }
}

// ---------------------------------------------------------------------------
// Kernel 2 (fallback, no workspace): same recurrence but computes the
// x-projection inline each step (thread also holds 32 W_x weights).
// ---------------------------------------------------------------------------
__global__ __launch_bounds__(1024) void ltc_inline(
    const float* __restrict__ x, const float* __restrict__ W,
    const float* __restrict__ bias, const float* __restrict__ tau,
    const float* __restrict__ A, const float* __restrict__ Wo,
    const float* __restrict__ bo, float* __restrict__ out)
{
  const int b = blockIdx.x;
  const int t = threadIdx.x;
  const int j = t & (H_ - 1);
  const int c = t >> 8;

  float wh[64], wx[32];
#pragma unroll
  for (int kk = 0; kk < 64; ++kk)
    wh[kk] = W[(I_ + c * 64 + kk) * H_ + j];
#pragma unroll
  for (int kk = 0; kk < 32; ++kk)
    wx[kk] = W[(c * 32 + kk) * H_ + j];

  __shared__ __align__(16) float hs[H_];
  __shared__ __align__(16) float xs[I_];
  __shared__ float ps[3][H_];

  float Aj = 0.f, itau = 0.f, bj = 0.f;
  if (c == 0) {
    Aj = A[j];
    itau = 1.0f / tau[j];
    bj = bias[j];
    hs[j] = 0.0f;
  }
  const float4* xrow4 = (const float4*)(x + (size_t)b * S_ * I_);
  if (t < 32) ((float4*)xs)[t] = xrow4[t];  // stage step 0
  __syncthreads();

  for (int step = 0; step < S_; ++step) {
    float4 xnext4 = make_float4(0.f, 0.f, 0.f, 0.f);
    if (t < 32) {
      const int snext = (step + 1 < S_) ? step + 1 : step;
      xnext4 = xrow4[snext * 32 + t];
    }

    float acc = 0.0f;
#pragma unroll
    for (int kk = 0; kk < 64; kk += 4) {
      float4 h4 = *(const float4*)&hs[c * 64 + kk];
      acc = fmaf(h4.x, wh[kk + 0], acc);
      acc = fmaf(h4.y, wh[kk + 1], acc);
      acc = fmaf(h4.z, wh[kk + 2], acc);
      acc = fmaf(h4.w, wh[kk + 3], acc);
    }
#pragma unroll
    for (int kk = 0; kk < 32; kk += 4) {
      float4 x4 = *(const float4*)&xs[c * 32 + kk];
      acc = fmaf(x4.x, wx[kk + 0], acc);
      acc = fmaf(x4.y, wx[kk + 1], acc);
      acc = fmaf(x4.z, wx[kk + 2], acc);
      acc = fmaf(x4.w, wx[kk + 3], acc);
    }

    if (c) ps[c - 1][j] = acc;
    __syncthreads();

    if (t < 32) ((float4*)xs)[t] = xnext4;  // safe: xs reads done pre-barrier
    if (c == 0) {
      const float z = acc + ps[0][j] + ps[1][j] + ps[2][j] + bj;
      const float f = tanhf(z);
      const float hj = hs[j];
      hs[j] = (hj + DT * f * Aj) / (1.0f + DT * (itau + f));
    }
    __syncthreads();
  }

  if (t < O_) {
    float acc = bo[t];
#pragma unroll 8
    for (int h = 0; h < H_; ++h)
      acc = fmaf(hs[h], Wo[h * O_ + t], acc);
    out[b * O_ + t] = acc;
  }
}

// ---------------------------------------------------------------------------
extern "C" void kernel_launch(void* const* d_in, const int* in_sizes, int n_in,
                              void* d_out, int out_size, void* d_ws, size_t ws_size,
                              hipStream_t stream) {
  const float* x   = (const float*)d_in[0];
  const float* W   = (const float*)d_in[1];
  const float* b   = (const float*)d_in[2];
  const float* tau = (const float*)d_in[3];
  const float* A   = (const float*)d_in[4];
  const float* Wo  = (const float*)d_in[5];
  const float* bo  = (const float*)d_in[6];
  float* out = (float*)d_out;

  const size_t XP_BYTES = (size_t)B_ * S_ * H_ * sizeof(float);

  if (ws_size >= XP_BYTES) {
    float* xp = (float*)d_ws;
    hipLaunchKernelGGL(xproj_kernel, dim3((B_ * S_) / RPB), dim3(256), 0, stream,
                       x, W, b, xp);
    hipLaunchKernelGGL(ltc_main, dim3(B_), dim3(1024), 0, stream,
                       xp, W, tau, A, Wo, bo, out);
  } else {
    hipLaunchKernelGGL(ltc_inline, dim3(B_), dim3(1024), 0, stream,
                       x, W, b, tau, A, Wo, bo, out);
  }
}

// Round 2
// 2830.253 us; speedup vs baseline: 1.2698x; 1.2698x over previous
//
#include <hip/hip_runtime.h>
#include <math.h>

#define DT    0.01f
#define B_    64
#define S_    4096
#define I_    128
#define H_    256
#define O_    128

// ---------------------------------------------------------------------------
// Kernel 1: xproj[b,t,j] = b[j] + sum_i x[b,t,i] * W[i,j]   (W rows 0..127)
// ---------------------------------------------------------------------------
#define RPB 64

__global__ __launch_bounds__(256, 2) void xproj_kernel(
    const float* __restrict__ x, const float* __restrict__ W,
    const float* __restrict__ bias, float* __restrict__ xp)
{
  __shared__ __align__(16) float xs[RPB][I_];
  const int j = threadIdx.x;

  float w[I_];
#pragma unroll
  for (int k = 0; k < I_; ++k) w[k] = W[k * H_ + j];
  const float bj = bias[j];

  const size_t row0 = (size_t)blockIdx.x * RPB;

  const float4* src4 = (const float4*)(x + row0 * I_);
  float4* xs4 = (float4*)&xs[0][0];
#pragma unroll
  for (int i = 0; i < (RPB * I_ / 4) / 256; ++i)
    xs4[j + i * 256] = src4[j + i * 256];
  __syncthreads();

  for (int r = 0; r < RPB; r += 4) {
    float a0 = bj, a1 = bj, a2 = bj, a3 = bj;
    const float4* r0 = (const float4*)xs[r + 0];
    const float4* r1 = (const float4*)xs[r + 1];
    const float4* r2 = (const float4*)xs[r + 2];
    const float4* r3 = (const float4*)xs[r + 3];
#pragma unroll
    for (int k4 = 0; k4 < I_ / 4; ++k4) {
      float4 v0 = r0[k4], v1 = r1[k4], v2 = r2[k4], v3 = r3[k4];
      a0 = fmaf(v0.x, w[4*k4+0], a0); a0 = fmaf(v0.y, w[4*k4+1], a0);
      a0 = fmaf(v0.z, w[4*k4+2], a0); a0 = fmaf(v0.w, w[4*k4+3], a0);
      a1 = fmaf(v1.x, w[4*k4+0], a1); a1 = fmaf(v1.y, w[4*k4+1], a1);
      a1 = fmaf(v1.z, w[4*k4+2], a1); a1 = fmaf(v1.w, w[4*k4+3], a1);
      a2 = fmaf(v2.x, w[4*k4+0], a2); a2 = fmaf(v2.y, w[4*k4+1], a2);
      a2 = fmaf(v2.z, w[4*k4+2], a2); a2 = fmaf(v2.w, w[4*k4+3], a2);
      a3 = fmaf(v3.x, w[4*k4+0], a3); a3 = fmaf(v3.y, w[4*k4+1], a3);
      a3 = fmaf(v3.z, w[4*k4+2], a3); a3 = fmaf(v3.w, w[4*k4+3], a3);
    }
    xp[(row0 + r + 0) * H_ + j] = a0;
    xp[(row0 + r + 1) * H_ + j] = a1;
    xp[(row0 + r + 2) * H_ + j] = a2;
    xp[(row0 + r + 3) * H_ + j] = a3;
  }
}

// ---------------------------------------------------------------------------
// Kernel 2: sequential LTC recurrence, one block per batch element.
// 1024 threads = 16 waves. Lane l of wave wv: output o = wv*16 + (l>>2),
// K-chunk q = l&3 (64 weights in registers). Per step:
//   - dot partial over the 64-element chunk (LDS broadcast reads, padded
//     68-float stride so the 4 q-addresses hit disjoint banks)
//   - 4-lane DPP quad-perm reduce (no LDS, no barrier)
//   - update computed redundantly on all 4 lanes (fast tanh via v_exp+v_rcp)
//   - q==0 lane writes h_new to the OTHER hs buffer; ONE __syncthreads.
// h[o] lives in registers. xp prefetched one step ahead.
// ---------------------------------------------------------------------------
#define PADH 68

__global__ __launch_bounds__(1024) void ltc_main(
    const float* __restrict__ xp, const float* __restrict__ W,
    const float* __restrict__ tau, const float* __restrict__ A,
    const float* __restrict__ Wo, const float* __restrict__ bo,
    float* __restrict__ out)
{
  const int b  = blockIdx.x;
  const int t  = threadIdx.x;
  const int wv = t >> 6;
  const int l  = t & 63;
  const int o  = wv * 16 + (l >> 2);  // output index 0..255
  const int q  = l & 3;               // K-chunk 0..3

  float w[64];
#pragma unroll
  for (int kk = 0; kk < 64; ++kk)
    w[kk] = W[(I_ + q * 64 + kk) * H_ + o];

  __shared__ __align__(16) float hs[2][4 * PADH];

  const float Aj   = A[o];
  const float itau = 1.0f / tau[o];
  const float dtA  = DT * Aj;
  const float base = 1.0f + DT * itau;

  const float* xprow = xp + (size_t)b * S_ * H_ + o;

  float h    = 0.0f;
  float xpre = xprow[0];
  const int po = (o >> 6) * PADH + (o & 63);
  if (q == 0) hs[0][po] = 0.0f;
  __syncthreads();

#define LTC_BODY(RB, WB, STEP)                                               \
  {                                                                          \
    const int snext = ((STEP) + 1 < S_) ? (STEP) + 1 : (STEP);               \
    const float xnext = xprow[(size_t)snext * H_];                           \
    float acc = 0.0f;                                                        \
    const float* hb = &hs[RB][q * PADH];                                     \
    _Pragma("unroll")                                                        \
    for (int kk = 0; kk < 64; kk += 4) {                                     \
      float4 h4 = *(const float4*)&hb[kk];                                   \
      acc = fmaf(h4.x, w[kk + 0], acc);                                      \
      acc = fmaf(h4.y, w[kk + 1], acc);                                      \
      acc = fmaf(h4.z, w[kk + 2], acc);                                      \
      acc = fmaf(h4.w, w[kk + 3], acc);                                      \
    }                                                                        \
    acc += __int_as_float(__builtin_amdgcn_mov_dpp(                          \
        __float_as_int(acc), 0xB1, 0xF, 0xF, true)); /* quad xor1 */         \
    acc += __int_as_float(__builtin_amdgcn_mov_dpp(                          \
        __float_as_int(acc), 0x4E, 0xF, 0xF, true)); /* quad xor2 */         \
    float z = acc + xpre;                                                    \
    z = fminf(15.0f, fmaxf(-15.0f, z));                                      \
    const float E = __expf(2.0f * z);                                        \
    const float f = (E - 1.0f) * __builtin_amdgcn_rcpf(E + 1.0f);            \
    h = fmaf(dtA, f, h) * __builtin_amdgcn_rcpf(fmaf(DT, f, base));          \
    if (q == 0) hs[WB][po] = h;                                              \
    xpre = xnext;                                                            \
    __syncthreads();                                                         \
  }

  for (int s = 0; s < S_; s += 2) {
    LTC_BODY(0, 1, s)
    LTC_BODY(1, 0, s + 1)
  }
#undef LTC_BODY

  // final h is in hs[0] (step 4095 writes buffer 0)
  if (t < O_) {
    float accO = bo[t];
#pragma unroll 8
    for (int hh = 0; hh < H_; ++hh) {
      const float hv = hs[0][(hh >> 6) * PADH + (hh & 63)];
      accO = fmaf(hv, Wo[hh * O_ + t], accO);
    }
    out[b * O_ + t] = accO;
  }
}

// ---------------------------------------------------------------------------
// Fallback (no workspace): previous proven structure with inline x-proj.
// ---------------------------------------------------------------------------
__global__ __launch_bounds__(1024) void ltc_inline(
    const float* __restrict__ x, const float* __restrict__ W,
    const float* __restrict__ bias, const float* __restrict__ tau,
    const float* __restrict__ A, const float* __restrict__ Wo,
    const float* __restrict__ bo, float* __restrict__ out)
{
  const int b = blockIdx.x;
  const int t = threadIdx.x;
  const int j = t & (H_ - 1);
  const int c = t >> 8;

  float wh[64], wx[32];
#pragma unroll
  for (int kk = 0; kk < 64; ++kk)
    wh[kk] = W[(I_ + c * 64 + kk) * H_ + j];
#pragma unroll
  for (int kk = 0; kk < 32; ++kk)
    wx[kk] = W[(c * 32 + kk) * H_ + j];

  __shared__ __align__(16) float hsf[H_];
  __shared__ __align__(16) float xsf[I_];
  __shared__ float ps[3][H_];

  float Aj = 0.f, itau = 0.f, bj = 0.f;
  if (c == 0) {
    Aj = A[j];
    itau = 1.0f / tau[j];
    bj = bias[j];
    hsf[j] = 0.0f;
  }
  const float4* xrow4 = (const float4*)(x + (size_t)b * S_ * I_);
  if (t < 32) ((float4*)xsf)[t] = xrow4[t];
  __syncthreads();

  for (int step = 0; step < S_; ++step) {
    float4 xnext4 = make_float4(0.f, 0.f, 0.f, 0.f);
    if (t < 32) {
      const int snext = (step + 1 < S_) ? step + 1 : step;
      xnext4 = xrow4[snext * 32 + t];
    }

    float acc = 0.0f;
#pragma unroll
    for (int kk = 0; kk < 64; kk += 4) {
      float4 h4 = *(const float4*)&hsf[c * 64 + kk];
      acc = fmaf(h4.x, wh[kk + 0], acc);
      acc = fmaf(h4.y, wh[kk + 1], acc);
      acc = fmaf(h4.z, wh[kk + 2], acc);
      acc = fmaf(h4.w, wh[kk + 3], acc);
    }
#pragma unroll
    for (int kk = 0; kk < 32; kk += 4) {
      float4 x4 = *(const float4*)&xsf[c * 32 + kk];
      acc = fmaf(x4.x, wx[kk + 0], acc);
      acc = fmaf(x4.y, wx[kk + 1], acc);
      acc = fmaf(x4.z, wx[kk + 2], acc);
      acc = fmaf(x4.w, wx[kk + 3], acc);
    }

    if (c) ps[c - 1][j] = acc;
    __syncthreads();

    if (t < 32) ((float4*)xsf)[t] = xnext4;
    if (c == 0) {
      const float z = acc + ps[0][j] + ps[1][j] + ps[2][j] + bj;
      const float f = tanhf(z);
      const float hj = hsf[j];
      hsf[j] = (hj + DT * f * Aj) / (1.0f + DT * (itau + f));
    }
    __syncthreads();
  }

  if (t < O_) {
    float acc = bo[t];
#pragma unroll 8
    for (int h = 0; h < H_; ++h)
      acc = fmaf(hsf[h], Wo[h * O_ + t], acc);
    out[b * O_ + t] = acc;
  }
}

// ---------------------------------------------------------------------------
extern "C" void kernel_launch(void* const* d_in, const int* in_sizes, int n_in,
                              void* d_out, int out_size, void* d_ws, size_t ws_size,
                              hipStream_t stream) {
  const float* x   = (const float*)d_in[0];
  const float* W   = (const float*)d_in[1];
  const float* b   = (const float*)d_in[2];
  const float* tau = (const float*)d_in[3];
  const float* A   = (const float*)d_in[4];
  const float* Wo  = (const float*)d_in[5];
  const float* bo  = (const float*)d_in[6];
  float* out = (float*)d_out;

  const size_t XP_BYTES = (size_t)B_ * S_ * H_ * sizeof(float);

  if (ws_size >= XP_BYTES) {
    float* xp = (float*)d_ws;
    hipLaunchKernelGGL(xproj_kernel, dim3((B_ * S_) / RPB), dim3(256), 0, stream,
                       x, W, b, xp);
    hipLaunchKernelGGL(ltc_main, dim3(B_), dim3(1024), 0, stream,
                       xp, W, tau, A, Wo, bo, out);
  } else {
    hipLaunchKernelGGL(ltc_inline, dim3(B_), dim3(1024), 0, stream,
                       x, W, b, tau, A, Wo, bo, out);
  }
}

// Round 3
// 2430.057 us; speedup vs baseline: 1.4789x; 1.1647x over previous
//
#include <hip/hip_runtime.h>
#include <math.h>

#define DT    0.01f
#define B_    64
#define S_    4096
#define I_    128
#define H_    256
#define O_    128

typedef _Float16 half2v __attribute__((ext_vector_type(2)));

#if defined(__has_builtin)
#if __has_builtin(__builtin_amdgcn_fdot2)
#define FDOT2(a, b, c) __builtin_amdgcn_fdot2((a), (b), (c), false)
#endif
#endif
#ifndef FDOT2
#define FDOT2(a, b, c) \
  fmaf((float)(a).x, (float)(b).x, fmaf((float)(a).y, (float)(b).y, (c)))
#endif

// ---------------------------------------------------------------------------
// Kernel 1: xproj[b,t,j] = b[j] + sum_i x[b,t,i] * W[i,j]   (W rows 0..127)
// ---------------------------------------------------------------------------
#define RPB 64

__global__ __launch_bounds__(256, 2) void xproj_kernel(
    const float* __restrict__ x, const float* __restrict__ W,
    const float* __restrict__ bias, float* __restrict__ xp)
{
  __shared__ __align__(16) float xs[RPB][I_];
  const int j = threadIdx.x;

  float w[I_];
#pragma unroll
  for (int k = 0; k < I_; ++k) w[k] = W[k * H_ + j];
  const float bj = bias[j];

  const size_t row0 = (size_t)blockIdx.x * RPB;

  const float4* src4 = (const float4*)(x + row0 * I_);
  float4* xs4 = (float4*)&xs[0][0];
#pragma unroll
  for (int i = 0; i < (RPB * I_ / 4) / 256; ++i)
    xs4[j + i * 256] = src4[j + i * 256];
  __syncthreads();

  for (int r = 0; r < RPB; r += 4) {
    float a0 = bj, a1 = bj, a2 = bj, a3 = bj;
    const float4* r0 = (const float4*)xs[r + 0];
    const float4* r1 = (const float4*)xs[r + 1];
    const float4* r2 = (const float4*)xs[r + 2];
    const float4* r3 = (const float4*)xs[r + 3];
#pragma unroll
    for (int k4 = 0; k4 < I_ / 4; ++k4) {
      float4 v0 = r0[k4], v1 = r1[k4], v2 = r2[k4], v3 = r3[k4];
      a0 = fmaf(v0.x, w[4*k4+0], a0); a0 = fmaf(v0.y, w[4*k4+1], a0);
      a0 = fmaf(v0.z, w[4*k4+2], a0); a0 = fmaf(v0.w, w[4*k4+3], a0);
      a1 = fmaf(v1.x, w[4*k4+0], a1); a1 = fmaf(v1.y, w[4*k4+1], a1);
      a1 = fmaf(v1.z, w[4*k4+2], a1); a1 = fmaf(v1.w, w[4*k4+3], a1);
      a2 = fmaf(v2.x, w[4*k4+0], a2); a2 = fmaf(v2.y, w[4*k4+1], a2);
      a2 = fmaf(v2.z, w[4*k4+2], a2); a2 = fmaf(v2.w, w[4*k4+3], a2);
      a3 = fmaf(v3.x, w[4*k4+0], a3); a3 = fmaf(v3.y, w[4*k4+1], a3);
      a3 = fmaf(v3.z, w[4*k4+2], a3); a3 = fmaf(v3.w, w[4*k4+3], a3);
    }
    xp[(row0 + r + 0) * H_ + j] = a0;
    xp[(row0 + r + 1) * H_ + j] = a1;
    xp[(row0 + r + 2) * H_ + j] = a2;
    xp[(row0 + r + 3) * H_ + j] = a3;
  }
}

// ---------------------------------------------------------------------------
// Kernel 2: LTC recurrence. 1024 threads = 16 waves, 1 block/CU (forced via
// launch_bounds(1024,4) -> 128 VGPR budget so weights stay register-resident).
// Lane l of wave wv: output o = wv*16+(l>>2), K-chunk q = l&3.
// h stored in LDS as packed f16 (chunk stride 72 f16 = 144B so the 4
// broadcast addresses per wave hit disjoint bank quads); dot product via
// v_dot2_f32_f16 (32 ops/lane), f32 accumulate. 4-lane DPP quad reduce,
// redundant fast update on all lanes, ONE __syncthreads per step.
// ---------------------------------------------------------------------------
#define CH 72  // f16 chunk stride

__global__ __launch_bounds__(1024, 4) void ltc_main(
    const float* __restrict__ xp, const float* __restrict__ W,
    const float* __restrict__ tau, const float* __restrict__ A,
    const float* __restrict__ Wo, const float* __restrict__ bo,
    float* __restrict__ out)
{
  const int b  = blockIdx.x;
  const int t  = threadIdx.x;
  const int wv = t >> 6;
  const int l  = t & 63;
  const int o  = wv * 16 + (l >> 2);  // output index 0..255
  const int q  = l & 3;               // K-chunk 0..3

  half2v wpk[32];
#pragma unroll
  for (int kk = 0; kk < 32; ++kk) {
    wpk[kk].x = (_Float16)W[(I_ + q * 64 + 2 * kk + 0) * H_ + o];
    wpk[kk].y = (_Float16)W[(I_ + q * 64 + 2 * kk + 1) * H_ + o];
  }

  __shared__ __align__(16) _Float16 hsh[2][4 * CH];
  __shared__ float hfin[H_];

  const float Aj   = A[o];
  const float itau = 1.0f / tau[o];
  const float dtA  = DT * Aj;
  const float base = 1.0f + DT * itau;

  const float* xprow = xp + (size_t)b * S_ * H_ + o;

  float h    = 0.0f;
  float xpre = xprow[0];
  const int po = (o >> 6) * CH + (o & 63);
  if (q == 0) hsh[0][po] = (_Float16)0.0f;
  __syncthreads();

#define LTC_BODY(RB, WB, STEP)                                               \
  {                                                                          \
    const int snext = ((STEP) + 1 < S_) ? (STEP) + 1 : (STEP);               \
    const float xnext = xprow[(size_t)snext * H_];                           \
    float acc = 0.0f;                                                        \
    const float4* hb = (const float4*)&hsh[RB][q * CH];                      \
    _Pragma("unroll")                                                        \
    for (int r8 = 0; r8 < 8; ++r8) {                                         \
      float4 v = hb[r8];                                                     \
      acc = FDOT2(__builtin_bit_cast(half2v, v.x), wpk[4 * r8 + 0], acc);    \
      acc = FDOT2(__builtin_bit_cast(half2v, v.y), wpk[4 * r8 + 1], acc);    \
      acc = FDOT2(__builtin_bit_cast(half2v, v.z), wpk[4 * r8 + 2], acc);    \
      acc = FDOT2(__builtin_bit_cast(half2v, v.w), wpk[4 * r8 + 3], acc);    \
    }                                                                        \
    acc += __int_as_float(__builtin_amdgcn_mov_dpp(                          \
        __float_as_int(acc), 0xB1, 0xF, 0xF, true)); /* quad xor1 */         \
    acc += __int_as_float(__builtin_amdgcn_mov_dpp(                          \
        __float_as_int(acc), 0x4E, 0xF, 0xF, true)); /* quad xor2 */         \
    float z = acc + xpre;                                                    \
    z = fminf(15.0f, fmaxf(-15.0f, z));                                      \
    const float E = __expf(2.0f * z);                                        \
    const float f = (E - 1.0f) * __builtin_amdgcn_rcpf(E + 1.0f);            \
    h = fmaf(dtA, f, h) * __builtin_amdgcn_rcpf(fmaf(DT, f, base));          \
    if (q == 0) hsh[WB][po] = (_Float16)h;                                   \
    xpre = xnext;                                                            \
    __syncthreads();                                                         \
  }

  for (int s = 0; s < S_; s += 2) {
    LTC_BODY(0, 1, s)
    LTC_BODY(1, 0, s + 1)
  }
#undef LTC_BODY

  // stage final f32 h, then fused output projection
  if (q == 0) hfin[o] = h;
  __syncthreads();

  if (t < O_) {
    float accO = bo[t];
#pragma unroll 8
    for (int hh = 0; hh < H_; ++hh)
      accO = fmaf(hfin[hh], Wo[hh * O_ + t], accO);
    out[b * O_ + t] = accO;
  }
}

// ---------------------------------------------------------------------------
// Fallback (no workspace): proven structure with inline x-proj.
// ---------------------------------------------------------------------------
__global__ __launch_bounds__(1024) void ltc_inline(
    const float* __restrict__ x, const float* __restrict__ W,
    const float* __restrict__ bias, const float* __restrict__ tau,
    const float* __restrict__ A, const float* __restrict__ Wo,
    const float* __restrict__ bo, float* __restrict__ out)
{
  const int b = blockIdx.x;
  const int t = threadIdx.x;
  const int j = t & (H_ - 1);
  const int c = t >> 8;

  float wh[64], wx[32];
#pragma unroll
  for (int kk = 0; kk < 64; ++kk)
    wh[kk] = W[(I_ + c * 64 + kk) * H_ + j];
#pragma unroll
  for (int kk = 0; kk < 32; ++kk)
    wx[kk] = W[(c * 32 + kk) * H_ + j];

  __shared__ __align__(16) float hsf[H_];
  __shared__ __align__(16) float xsf[I_];
  __shared__ float ps[3][H_];

  float Aj = 0.f, itau = 0.f, bj = 0.f;
  if (c == 0) {
    Aj = A[j];
    itau = 1.0f / tau[j];
    bj = bias[j];
    hsf[j] = 0.0f;
  }
  const float4* xrow4 = (const float4*)(x + (size_t)b * S_ * I_);
  if (t < 32) ((float4*)xsf)[t] = xrow4[t];
  __syncthreads();

  for (int step = 0; step < S_; ++step) {
    float4 xnext4 = make_float4(0.f, 0.f, 0.f, 0.f);
    if (t < 32) {
      const int snext = (step + 1 < S_) ? step + 1 : step;
      xnext4 = xrow4[snext * 32 + t];
    }

    float acc = 0.0f;
#pragma unroll
    for (int kk = 0; kk < 64; kk += 4) {
      float4 h4 = *(const float4*)&hsf[c * 64 + kk];
      acc = fmaf(h4.x, wh[kk + 0], acc);
      acc = fmaf(h4.y, wh[kk + 1], acc);
      acc = fmaf(h4.z, wh[kk + 2], acc);
      acc = fmaf(h4.w, wh[kk + 3], acc);
    }
#pragma unroll
    for (int kk = 0; kk < 32; kk += 4) {
      float4 x4 = *(const float4*)&xsf[c * 32 + kk];
      acc = fmaf(x4.x, wx[kk + 0], acc);
      acc = fmaf(x4.y, wx[kk + 1], acc);
      acc = fmaf(x4.z, wx[kk + 2], acc);
      acc = fmaf(x4.w, wx[kk + 3], acc);
    }

    if (c) ps[c - 1][j] = acc;
    __syncthreads();

    if (t < 32) ((float4*)xsf)[t] = xnext4;
    if (c == 0) {
      const float z = acc + ps[0][j] + ps[1][j] + ps[2][j] + bj;
      const float f = tanhf(z);
      const float hj = hsf[j];
      hsf[j] = (hj + DT * f * Aj) / (1.0f + DT * (itau + f));
    }
    __syncthreads();
  }

  if (t < O_) {
    float acc = bo[t];
#pragma unroll 8
    for (int h = 0; h < H_; ++h)
      acc = fmaf(hsf[h], Wo[h * O_ + t], acc);
    out[b * O_ + t] = acc;
  }
}

// ---------------------------------------------------------------------------
extern "C" void kernel_launch(void* const* d_in, const int* in_sizes, int n_in,
                              void* d_out, int out_size, void* d_ws, size_t ws_size,
                              hipStream_t stream) {
  const float* x   = (const float*)d_in[0];
  const float* W   = (const float*)d_in[1];
  const float* b   = (const float*)d_in[2];
  const float* tau = (const float*)d_in[3];
  const float* A   = (const float*)d_in[4];
  const float* Wo  = (const float*)d_in[5];
  const float* bo  = (const float*)d_in[6];
  float* out = (float*)d_out;

  const size_t XP_BYTES = (size_t)B_ * S_ * H_ * sizeof(float);

  if (ws_size >= XP_BYTES) {
    float* xp = (float*)d_ws;
    hipLaunchKernelGGL(xproj_kernel, dim3((B_ * S_) / RPB), dim3(256), 0, stream,
                       x, W, b, xp);
    hipLaunchKernelGGL(ltc_main, dim3(B_), dim3(1024), 0, stream,
                       xp, W, tau, A, Wo, bo, out);
  } else {
    hipLaunchKernelGGL(ltc_inline, dim3(B_), dim3(1024), 0, stream,
                       x, W, b, tau, A, Wo, bo, out);
  }
}

// Round 4
// 2334.044 us; speedup vs baseline: 1.5398x; 1.0411x over previous
//
#include <hip/hip_runtime.h>
#include <math.h>

#define DT    0.01f
#define B_    64
#define S_    4096
#define I_    128
#define H_    256
#define O_    128

typedef _Float16 f16x8 __attribute__((ext_vector_type(8)));
typedef float    f32x4 __attribute__((ext_vector_type(4)));

// ---------------------------------------------------------------------------
// Kernel 1: xproj[b,t,j] = b[j] + sum_i x[b,t,i] * W[i,j]   (W rows 0..127)
// ---------------------------------------------------------------------------
#define RPB 64

__global__ __launch_bounds__(256, 2) void xproj_kernel(
    const float* __restrict__ x, const float* __restrict__ W,
    const float* __restrict__ bias, float* __restrict__ xp)
{
  __shared__ __align__(16) float xs[RPB][I_];
  const int j = threadIdx.x;

  float w[I_];
#pragma unroll
  for (int k = 0; k < I_; ++k) w[k] = W[k * H_ + j];
  const float bj = bias[j];

  const size_t row0 = (size_t)blockIdx.x * RPB;

  const float4* src4 = (const float4*)(x + row0 * I_);
  float4* xs4 = (float4*)&xs[0][0];
#pragma unroll
  for (int i = 0; i < (RPB * I_ / 4) / 256; ++i)
    xs4[j + i * 256] = src4[j + i * 256];
  __syncthreads();

  for (int r = 0; r < RPB; r += 4) {
    float a0 = bj, a1 = bj, a2 = bj, a3 = bj;
    const float4* r0 = (const float4*)xs[r + 0];
    const float4* r1 = (const float4*)xs[r + 1];
    const float4* r2 = (const float4*)xs[r + 2];
    const float4* r3 = (const float4*)xs[r + 3];
#pragma unroll
    for (int k4 = 0; k4 < I_ / 4; ++k4) {
      float4 v0 = r0[k4], v1 = r1[k4], v2 = r2[k4], v3 = r3[k4];
      a0 = fmaf(v0.x, w[4*k4+0], a0); a0 = fmaf(v0.y, w[4*k4+1], a0);
      a0 = fmaf(v0.z, w[4*k4+2], a0); a0 = fmaf(v0.w, w[4*k4+3], a0);
      a1 = fmaf(v1.x, w[4*k4+0], a1); a1 = fmaf(v1.y, w[4*k4+1], a1);
      a1 = fmaf(v1.z, w[4*k4+2], a1); a1 = fmaf(v1.w, w[4*k4+3], a1);
      a2 = fmaf(v2.x, w[4*k4+0], a2); a2 = fmaf(v2.y, w[4*k4+1], a2);
      a2 = fmaf(v2.z, w[4*k4+2], a2); a2 = fmaf(v2.w, w[4*k4+3], a2);
      a3 = fmaf(v3.x, w[4*k4+0], a3); a3 = fmaf(v3.y, w[4*k4+1], a3);
      a3 = fmaf(v3.z, w[4*k4+2], a3); a3 = fmaf(v3.w, w[4*k4+3], a3);
    }
    xp[(row0 + r + 0) * H_ + j] = a0;
    xp[(row0 + r + 1) * H_ + j] = a1;
    xp[(row0 + r + 2) * H_ + j] = a2;
    xp[(row0 + r + 3) * H_ + j] = a3;
  }
}

// ---------------------------------------------------------------------------
// Kernel 2: LTC recurrence via MFMA. 1024 threads = 16 waves, 1 block/CU.
// Wave wv owns outputs o in [wv*16, wv*16+16); lane l -> col = l&15.
// Per step:
//   A-fragment (h, f16) read from LDS with uniform rows: every lane in a
//     16-lane group loads the same 8 contiguous k-values -> all 16 A rows
//     identical -> every C row/reg equals the true GEMV result for its col.
//   B-fragment (W_h, f16) register-resident: b[kt][j] =
//     W[I_+kt*32+(l>>4)*8+j][wv*16+(l&15)], 32 VGPRs.
//   Two 4-deep MFMA chains (acc0 seeded with xpre as C-in, acc1 with 0).
//   Fast update (exp+rcp) redundantly on all lanes; lanes 0..15 write h'
//   (f16) to the other LDS buffer; ONE __syncthreads per step.
// ---------------------------------------------------------------------------
__global__ __launch_bounds__(1024, 4) void ltc_main(
    const float* __restrict__ xp, const float* __restrict__ W,
    const float* __restrict__ tau, const float* __restrict__ A,
    const float* __restrict__ Wo, const float* __restrict__ bo,
    float* __restrict__ out)
{
  const int b  = blockIdx.x;
  const int t  = threadIdx.x;
  const int wv = t >> 6;
  const int l  = t & 63;
  const int g  = l >> 4;              // k-group 0..3
  const int o  = wv * 16 + (l & 15);  // this lane's output column

  // B-operand weights: W_h[k][o] for k-slice of each of the 8 K-tiles
  f16x8 bw[8];
#pragma unroll
  for (int kt = 0; kt < 8; ++kt)
#pragma unroll
    for (int j = 0; j < 8; ++j)
      bw[kt][j] = (_Float16)W[(I_ + kt * 32 + g * 8 + j) * H_ + o];

  __shared__ __align__(16) _Float16 hs[2][H_];
  __shared__ float hfin[H_];

  const float Aj   = A[o];
  const float itau = 1.0f / tau[o];
  const float dtA  = DT * Aj;
  const float base = 1.0f + DT * itau;

  const float* xprow = xp + (size_t)b * S_ * H_ + o;

  float h    = 0.0f;
  float xpre = xprow[0];
  if (l < 16) hs[0][wv * 16 + l] = (_Float16)0.0f;
  __syncthreads();

#define LTC_BODY(RB, WB, STEP)                                               \
  {                                                                          \
    const int snext = ((STEP) + 1 < S_) ? (STEP) + 1 : (STEP);               \
    const float xnext = xprow[(size_t)snext * H_];                           \
    const _Float16* hb = &hs[RB][g * 8];                                     \
    f32x4 acc0 = {xpre, xpre, xpre, xpre};                                   \
    f32x4 acc1 = {0.0f, 0.0f, 0.0f, 0.0f};                                   \
    _Pragma("unroll")                                                        \
    for (int kt = 0; kt < 8; kt += 2) {                                      \
      f16x8 a0 = *(const f16x8*)(hb + (kt + 0) * 32);                        \
      f16x8 a1 = *(const f16x8*)(hb + (kt + 1) * 32);                        \
      acc0 = __builtin_amdgcn_mfma_f32_16x16x32_f16(a0, bw[kt + 0], acc0,    \
                                                    0, 0, 0);                \
      acc1 = __builtin_amdgcn_mfma_f32_16x16x32_f16(a1, bw[kt + 1], acc1,    \
                                                    0, 0, 0);                \
    }                                                                        \
    float z = acc0[0] + acc1[0];                                             \
    z = fminf(15.0f, fmaxf(-15.0f, z));                                      \
    const float E = __expf(2.0f * z);                                        \
    const float f = (E - 1.0f) * __builtin_amdgcn_rcpf(E + 1.0f);            \
    h = fmaf(dtA, f, h) * __builtin_amdgcn_rcpf(fmaf(DT, f, base));          \
    if (l < 16) hs[WB][wv * 16 + l] = (_Float16)h;                           \
    xpre = xnext;                                                            \
    __syncthreads();                                                         \
  }

  for (int s = 0; s < S_; s += 2) {
    LTC_BODY(0, 1, s)
    LTC_BODY(1, 0, s + 1)
  }
#undef LTC_BODY

  // stage final f32 h, then fused output projection
  if (l < 16) hfin[wv * 16 + l] = h;
  __syncthreads();

  if (t < O_) {
    float accO = bo[t];
#pragma unroll 8
    for (int hh = 0; hh < H_; ++hh)
      accO = fmaf(hfin[hh], Wo[hh * O_ + t], accO);
    out[b * O_ + t] = accO;
  }
}

// ---------------------------------------------------------------------------
// Fallback (no workspace): proven structure with inline x-proj.
// ---------------------------------------------------------------------------
__global__ __launch_bounds__(1024) void ltc_inline(
    const float* __restrict__ x, const float* __restrict__ W,
    const float* __restrict__ bias, const float* __restrict__ tau,
    const float* __restrict__ A, const float* __restrict__ Wo,
    const float* __restrict__ bo, float* __restrict__ out)
{
  const int b = blockIdx.x;
  const int t = threadIdx.x;
  const int j = t & (H_ - 1);
  const int c = t >> 8;

  float wh[64], wx[32];
#pragma unroll
  for (int kk = 0; kk < 64; ++kk)
    wh[kk] = W[(I_ + c * 64 + kk) * H_ + j];
#pragma unroll
  for (int kk = 0; kk < 32; ++kk)
    wx[kk] = W[(c * 32 + kk) * H_ + j];

  __shared__ __align__(16) float hsf[H_];
  __shared__ __align__(16) float xsf[I_];
  __shared__ float ps[3][H_];

  float Aj = 0.f, itau = 0.f, bj = 0.f;
  if (c == 0) {
    Aj = A[j];
    itau = 1.0f / tau[j];
    bj = bias[j];
    hsf[j] = 0.0f;
  }
  const float4* xrow4 = (const float4*)(x + (size_t)b * S_ * I_);
  if (t < 32) ((float4*)xsf)[t] = xrow4[t];
  __syncthreads();

  for (int step = 0; step < S_; ++step) {
    float4 xnext4 = make_float4(0.f, 0.f, 0.f, 0.f);
    if (t < 32) {
      const int snext = (step + 1 < S_) ? step + 1 : step;
      xnext4 = xrow4[snext * 32 + t];
    }

    float acc = 0.0f;
#pragma unroll
    for (int kk = 0; kk < 64; kk += 4) {
      float4 h4 = *(const float4*)&hsf[c * 64 + kk];
      acc = fmaf(h4.x, wh[kk + 0], acc);
      acc = fmaf(h4.y, wh[kk + 1], acc);
      acc = fmaf(h4.z, wh[kk + 2], acc);
      acc = fmaf(h4.w, wh[kk + 3], acc);
    }
#pragma unroll
    for (int kk = 0; kk < 32; kk += 4) {
      float4 x4 = *(const float4*)&xsf[c * 32 + kk];
      acc = fmaf(x4.x, wx[kk + 0], acc);
      acc = fmaf(x4.y, wx[kk + 1], acc);
      acc = fmaf(x4.z, wx[kk + 2], acc);
      acc = fmaf(x4.w, wx[kk + 3], acc);
    }

    if (c) ps[c - 1][j] = acc;
    __syncthreads();

    if (t < 32) ((float4*)xsf)[t] = xnext4;
    if (c == 0) {
      const float z = acc + ps[0][j] + ps[1][j] + ps[2][j] + bj;
      const float f = tanhf(z);
      const float hj = hsf[j];
      hsf[j] = (hj + DT * f * Aj) / (1.0f + DT * (itau + f));
    }
    __syncthreads();
  }

  if (t < O_) {
    float acc = bo[t];
#pragma unroll 8
    for (int h = 0; h < H_; ++h)
      acc = fmaf(hsf[h], Wo[h * O_ + t], acc);
    out[b * O_ + t] = acc;
  }
}

// ---------------------------------------------------------------------------
extern "C" void kernel_launch(void* const* d_in, const int* in_sizes, int n_in,
                              void* d_out, int out_size, void* d_ws, size_t ws_size,
                              hipStream_t stream) {
  const float* x   = (const float*)d_in[0];
  const float* W   = (const float*)d_in[1];
  const float* b   = (const float*)d_in[2];
  const float* tau = (const float*)d_in[3];
  const float* A   = (const float*)d_in[4];
  const float* Wo  = (const float*)d_in[5];
  const float* bo  = (const float*)d_in[6];
  float* out = (float*)d_out;

  const size_t XP_BYTES = (size_t)B_ * S_ * H_ * sizeof(float);

  if (ws_size >= XP_BYTES) {
    float* xp = (float*)d_ws;
    hipLaunchKernelGGL(xproj_kernel, dim3((B_ * S_) / RPB), dim3(256), 0, stream,
                       x, W, b, xp);
    hipLaunchKernelGGL(ltc_main, dim3(B_), dim3(1024), 0, stream,
                       xp, W, tau, A, Wo, bo, out);
  } else {
    hipLaunchKernelGGL(ltc_inline, dim3(B_), dim3(1024), 0, stream,
                       x, W, b, tau, A, Wo, bo, out);
  }
}

// Round 5
// 1899.985 us; speedup vs baseline: 1.8915x; 1.2285x over previous
//
#include <hip/hip_runtime.h>
#include <math.h>

#define DT    0.01f
#define B_    64
#define S_    4096
#define I_    128
#define H_    256
#define O_    128

typedef _Float16 f16x8 __attribute__((ext_vector_type(8)));
typedef float    f32x4 __attribute__((ext_vector_type(4)));

// ---------------------------------------------------------------------------
// Kernel 1: xproj[b,t,j] = b[j] + sum_i x[b,t,i] * W[i,j]   (W rows 0..127)
// ---------------------------------------------------------------------------
#define RPB 64

__global__ __launch_bounds__(256, 2) void xproj_kernel(
    const float* __restrict__ x, const float* __restrict__ W,
    const float* __restrict__ bias, float* __restrict__ xp)
{
  __shared__ __align__(16) float xs[RPB][I_];
  const int j = threadIdx.x;

  float w[I_];
#pragma unroll
  for (int k = 0; k < I_; ++k) w[k] = W[k * H_ + j];
  const float bj = bias[j];

  const size_t row0 = (size_t)blockIdx.x * RPB;

  const float4* src4 = (const float4*)(x + row0 * I_);
  float4* xs4 = (float4*)&xs[0][0];
#pragma unroll
  for (int i = 0; i < (RPB * I_ / 4) / 256; ++i)
    xs4[j + i * 256] = src4[j + i * 256];
  __syncthreads();

  for (int r = 0; r < RPB; r += 4) {
    float a0 = bj, a1 = bj, a2 = bj, a3 = bj;
    const float4* r0 = (const float4*)xs[r + 0];
    const float4* r1 = (const float4*)xs[r + 1];
    const float4* r2 = (const float4*)xs[r + 2];
    const float4* r3 = (const float4*)xs[r + 3];
#pragma unroll
    for (int k4 = 0; k4 < I_ / 4; ++k4) {
      float4 v0 = r0[k4], v1 = r1[k4], v2 = r2[k4], v3 = r3[k4];
      a0 = fmaf(v0.x, w[4*k4+0], a0); a0 = fmaf(v0.y, w[4*k4+1], a0);
      a0 = fmaf(v0.z, w[4*k4+2], a0); a0 = fmaf(v0.w, w[4*k4+3], a0);
      a1 = fmaf(v1.x, w[4*k4+0], a1); a1 = fmaf(v1.y, w[4*k4+1], a1);
      a1 = fmaf(v1.z, w[4*k4+2], a1); a1 = fmaf(v1.w, w[4*k4+3], a1);
      a2 = fmaf(v2.x, w[4*k4+0], a2); a2 = fmaf(v2.y, w[4*k4+1], a2);
      a2 = fmaf(v2.z, w[4*k4+2], a2); a2 = fmaf(v2.w, w[4*k4+3], a2);
      a3 = fmaf(v3.x, w[4*k4+0], a3); a3 = fmaf(v3.y, w[4*k4+1], a3);
      a3 = fmaf(v3.z, w[4*k4+2], a3); a3 = fmaf(v3.w, w[4*k4+3], a3);
    }
    xp[(row0 + r + 0) * H_ + j] = a0;
    xp[(row0 + r + 1) * H_ + j] = a1;
    xp[(row0 + r + 2) * H_ + j] = a2;
    xp[(row0 + r + 3) * H_ + j] = a3;
  }
}

// ---------------------------------------------------------------------------
// Kernel 2: LTC recurrence via MFMA, 256 threads = 4 waves (1/SIMD).
// Wave wv owns outputs [wv*64, wv*64+64) via 4 B-fragment sets (sg=0..3,
// cols wv*64+sg*16+(l&15)). All sets share the SAME A-fragments (h), so
// per step: 8 broadcast ds_read_b128 + 32 MFMA (8 interleaved 4-deep
// chains). Lane l then selects chain sg=l>>4 via cndmask -> each lane
// updates exactly ITS output o = wv*64+l (zero redundancy), writes f16 h'
// contiguously, ONE barrier across 4 waves. xpre is a per-lane coalesced
// load added after the select.
// Fragment k-mapping (HW-verified by round-4 bench): lane l's element j of
// A/B covers k = (l>>4)*8 + j; B col = l&15.
// ---------------------------------------------------------------------------
__global__ __launch_bounds__(256, 1) void ltc_main(
    const float* __restrict__ xp, const float* __restrict__ W,
    const float* __restrict__ tau, const float* __restrict__ A,
    const float* __restrict__ Wo, const float* __restrict__ bo,
    float* __restrict__ out)
{
  const int b  = blockIdx.x;
  const int t  = threadIdx.x;
  const int wv = t >> 6;   // 0..3
  const int l  = t & 63;
  const int g  = l >> 4;   // k-slice group 0..3 (also: which chain this lane keeps)
  const int c  = l & 15;   // col within 16-group
  const int o  = wv * 64 + l;  // this lane's unique output

  // B-fragments: 4 output groups x 8 K-tiles, register/AGPR-resident
  f16x8 bw[4][8];
#pragma unroll
  for (int sg = 0; sg < 4; ++sg)
#pragma unroll
    for (int kt = 0; kt < 8; ++kt)
#pragma unroll
      for (int j = 0; j < 8; ++j)
        bw[sg][kt][j] =
            (_Float16)W[(I_ + kt * 32 + g * 8 + j) * H_ + (wv * 64 + sg * 16 + c)];

  __shared__ __align__(16) _Float16 hs[2][H_];
  __shared__ float hfin[H_];

  const float Aj   = A[o];
  const float itau = 1.0f / tau[o];
  const float dtA  = DT * Aj;
  const float base = 1.0f + DT * itau;

  const float* xprow = xp + (size_t)b * S_ * H_ + o;

  float h    = 0.0f;
  float xpre = xprow[0];
  hs[0][t] = (_Float16)0.0f;
  __syncthreads();

#define LTC_BODY(RB, WB, STEP)                                               \
  {                                                                          \
    const int snext = ((STEP) + 1 < S_) ? (STEP) + 1 : (STEP);               \
    const float xnext = xprow[(size_t)snext * H_];                           \
    const _Float16* hb = &hs[RB][g * 8];                                     \
    f16x8 a[8];                                                              \
    _Pragma("unroll")                                                        \
    for (int kt = 0; kt < 8; ++kt) a[kt] = *(const f16x8*)(hb + kt * 32);    \
    f32x4 ac[4][2];                                                          \
    _Pragma("unroll")                                                        \
    for (int sg = 0; sg < 4; ++sg) {                                         \
      ac[sg][0] = (f32x4){0.f, 0.f, 0.f, 0.f};                               \
      ac[sg][1] = (f32x4){0.f, 0.f, 0.f, 0.f};                               \
    }                                                                        \
    _Pragma("unroll")                                                        \
    for (int kt = 0; kt < 8; ++kt) {                                         \
      _Pragma("unroll")                                                      \
      for (int sg = 0; sg < 4; ++sg)                                         \
        ac[sg][kt >> 2] = __builtin_amdgcn_mfma_f32_16x16x32_f16(            \
            a[kt], bw[sg][kt], ac[sg][kt >> 2], 0, 0, 0);                    \
    }                                                                        \
    const float z0 = ac[0][0][0] + ac[0][1][0];                              \
    const float z1 = ac[1][0][0] + ac[1][1][0];                              \
    const float z2 = ac[2][0][0] + ac[2][1][0];                              \
    const float z3 = ac[3][0][0] + ac[3][1][0];                              \
    const float za = (g & 1) ? z1 : z0;                                      \
    const float zb = (g & 1) ? z3 : z2;                                      \
    float z = ((g & 2) ? zb : za) + xpre;                                    \
    z = fminf(15.0f, fmaxf(-15.0f, z));                                      \
    const float E = __expf(2.0f * z);                                        \
    const float f = (E - 1.0f) * __builtin_amdgcn_rcpf(E + 1.0f);            \
    h = fmaf(dtA, f, h) * __builtin_amdgcn_rcpf(fmaf(DT, f, base));          \
    hs[WB][t] = (_Float16)h;                                                 \
    xpre = xnext;                                                            \
    __syncthreads();                                                         \
  }

  for (int st = 0; st < S_; st += 2) {
    LTC_BODY(0, 1, st)
    LTC_BODY(1, 0, st + 1)
  }
#undef LTC_BODY

  // stage final f32 h, then fused output projection
  hfin[t] = h;
  __syncthreads();

  if (t < O_) {
    float accO = bo[t];
#pragma unroll 8
    for (int hh = 0; hh < H_; ++hh)
      accO = fmaf(hfin[hh], Wo[hh * O_ + t], accO);
    out[b * O_ + t] = accO;
  }
}

// ---------------------------------------------------------------------------
// Fallback (no workspace): proven structure with inline x-proj.
// ---------------------------------------------------------------------------
__global__ __launch_bounds__(1024) void ltc_inline(
    const float* __restrict__ x, const float* __restrict__ W,
    const float* __restrict__ bias, const float* __restrict__ tau,
    const float* __restrict__ A, const float* __restrict__ Wo,
    const float* __restrict__ bo, float* __restrict__ out)
{
  const int b = blockIdx.x;
  const int t = threadIdx.x;
  const int j = t & (H_ - 1);
  const int c = t >> 8;

  float wh[64], wx[32];
#pragma unroll
  for (int kk = 0; kk < 64; ++kk)
    wh[kk] = W[(I_ + c * 64 + kk) * H_ + j];
#pragma unroll
  for (int kk = 0; kk < 32; ++kk)
    wx[kk] = W[(c * 32 + kk) * H_ + j];

  __shared__ __align__(16) float hsf[H_];
  __shared__ __align__(16) float xsf[I_];
  __shared__ float ps[3][H_];

  float Aj = 0.f, itau = 0.f, bj = 0.f;
  if (c == 0) {
    Aj = A[j];
    itau = 1.0f / tau[j];
    bj = bias[j];
    hsf[j] = 0.0f;
  }
  const float4* xrow4 = (const float4*)(x + (size_t)b * S_ * I_);
  if (t < 32) ((float4*)xsf)[t] = xrow4[t];
  __syncthreads();

  for (int step = 0; step < S_; ++step) {
    float4 xnext4 = make_float4(0.f, 0.f, 0.f, 0.f);
    if (t < 32) {
      const int snext = (step + 1 < S_) ? step + 1 : step;
      xnext4 = xrow4[snext * 32 + t];
    }

    float acc = 0.0f;
#pragma unroll
    for (int kk = 0; kk < 64; kk += 4) {
      float4 h4 = *(const float4*)&hsf[c * 64 + kk];
      acc = fmaf(h4.x, wh[kk + 0], acc);
      acc = fmaf(h4.y, wh[kk + 1], acc);
      acc = fmaf(h4.z, wh[kk + 2], acc);
      acc = fmaf(h4.w, wh[kk + 3], acc);
    }
#pragma unroll
    for (int kk = 0; kk < 32; kk += 4) {
      float4 x4 = *(const float4*)&xsf[c * 32 + kk];
      acc = fmaf(x4.x, wx[kk + 0], acc);
      acc = fmaf(x4.y, wx[kk + 1], acc);
      acc = fmaf(x4.z, wx[kk + 2], acc);
      acc = fmaf(x4.w, wx[kk + 3], acc);
    }

    if (c) ps[c - 1][j] = acc;
    __syncthreads();

    if (t < 32) ((float4*)xsf)[t] = xnext4;
    if (c == 0) {
      const float z = acc + ps[0][j] + ps[1][j] + ps[2][j] + bj;
      const float f = tanhf(z);
      const float hj = hsf[j];
      hsf[j] = (hj + DT * f * Aj) / (1.0f + DT * (itau + f));
    }
    __syncthreads();
  }

  if (t < O_) {
    float acc = bo[t];
#pragma unroll 8
    for (int h = 0; h < H_; ++h)
      acc = fmaf(hsf[h], Wo[h * O_ + t], acc);
    out[b * O_ + t] = acc;
  }
}

// ---------------------------------------------------------------------------
extern "C" void kernel_launch(void* const* d_in, const int* in_sizes, int n_in,
                              void* d_out, int out_size, void* d_ws, size_t ws_size,
                              hipStream_t stream) {
  const float* x   = (const float*)d_in[0];
  const float* W   = (const float*)d_in[1];
  const float* b   = (const float*)d_in[2];
  const float* tau = (const float*)d_in[3];
  const float* A   = (const float*)d_in[4];
  const float* Wo  = (const float*)d_in[5];
  const float* bo  = (const float*)d_in[6];
  float* out = (float*)d_out;

  const size_t XP_BYTES = (size_t)B_ * S_ * H_ * sizeof(float);

  if (ws_size >= XP_BYTES) {
    float* xp = (float*)d_ws;
    hipLaunchKernelGGL(xproj_kernel, dim3((B_ * S_) / RPB), dim3(256), 0, stream,
                       x, W, b, xp);
    hipLaunchKernelGGL(ltc_main, dim3(B_), dim3(256), 0, stream,
                       xp, W, tau, A, Wo, bo, out);
  } else {
    hipLaunchKernelGGL(ltc_inline, dim3(B_), dim3(1024), 0, stream,
                       x, W, b, tau, A, Wo, bo, out);
  }
}

// Round 6
// 1804.709 us; speedup vs baseline: 1.9914x; 1.0528x over previous
//
#include <hip/hip_runtime.h>
#include <math.h>

#define DT    0.01f
#define B_    64
#define S_    4096
#define I_    128
#define H_    256
#define O_    128

typedef _Float16 f16x8 __attribute__((ext_vector_type(8)));
typedef float    f32x4 __attribute__((ext_vector_type(4)));

// ---------------------------------------------------------------------------
// Kernel 1: xproj[b,t,j] = b[j] + sum_i x[b,t,i] * W[i,j]   (W rows 0..127)
// ---------------------------------------------------------------------------
#define RPB 64

__global__ __launch_bounds__(256, 2) void xproj_kernel(
    const float* __restrict__ x, const float* __restrict__ W,
    const float* __restrict__ bias, float* __restrict__ xp)
{
  __shared__ __align__(16) float xs[RPB][I_];
  const int j = threadIdx.x;

  float w[I_];
#pragma unroll
  for (int k = 0; k < I_; ++k) w[k] = W[k * H_ + j];
  const float bj = bias[j];

  const size_t row0 = (size_t)blockIdx.x * RPB;

  const float4* src4 = (const float4*)(x + row0 * I_);
  float4* xs4 = (float4*)&xs[0][0];
#pragma unroll
  for (int i = 0; i < (RPB * I_ / 4) / 256; ++i)
    xs4[j + i * 256] = src4[j + i * 256];
  __syncthreads();

  for (int r = 0; r < RPB; r += 4) {
    float a0 = bj, a1 = bj, a2 = bj, a3 = bj;
    const float4* r0 = (const float4*)xs[r + 0];
    const float4* r1 = (const float4*)xs[r + 1];
    const float4* r2 = (const float4*)xs[r + 2];
    const float4* r3 = (const float4*)xs[r + 3];
#pragma unroll
    for (int k4 = 0; k4 < I_ / 4; ++k4) {
      float4 v0 = r0[k4], v1 = r1[k4], v2 = r2[k4], v3 = r3[k4];
      a0 = fmaf(v0.x, w[4*k4+0], a0); a0 = fmaf(v0.y, w[4*k4+1], a0);
      a0 = fmaf(v0.z, w[4*k4+2], a0); a0 = fmaf(v0.w, w[4*k4+3], a0);
      a1 = fmaf(v1.x, w[4*k4+0], a1); a1 = fmaf(v1.y, w[4*k4+1], a1);
      a1 = fmaf(v1.z, w[4*k4+2], a1); a1 = fmaf(v1.w, w[4*k4+3], a1);
      a2 = fmaf(v2.x, w[4*k4+0], a2); a2 = fmaf(v2.y, w[4*k4+1], a2);
      a2 = fmaf(v2.z, w[4*k4+2], a2); a2 = fmaf(v2.w, w[4*k4+3], a2);
      a3 = fmaf(v3.x, w[4*k4+0], a3); a3 = fmaf(v3.y, w[4*k4+1], a3);
      a3 = fmaf(v3.z, w[4*k4+2], a3); a3 = fmaf(v3.w, w[4*k4+3], a3);
    }
    xp[(row0 + r + 0) * H_ + j] = a0;
    xp[(row0 + r + 1) * H_ + j] = a1;
    xp[(row0 + r + 2) * H_ + j] = a2;
    xp[(row0 + r + 3) * H_ + j] = a3;
  }
}

// ---------------------------------------------------------------------------
// Kernel 2: LTC recurrence via MFMA, 512 threads = 8 waves (2/SIMD).
// Wave wv owns 32 outputs [wv*32, wv*32+32) = 2 col-groups x 8 K-tiles =
// 16 MFMA/wave (32/SIMD = ~512cy matrix-pipe/step, the structural floor).
// 2 waves/SIMD let one wave's serial tail (acc-read, update, ds latency)
// interleave with the other's MFMA issue; setprio(1) wraps the MFMA cluster.
// C-in is seeded with this lane's xpre (no post-add). Lane l keeps chain
// s=l>>5, col c=l&15 -> output o = wv*32+s*16+c (2 lanes per output, update
// 2x redundant in-wave = free). Lanes with (l&16)==0 write h' (f16).
// ONE __syncthreads per step. Fragment k-mapping as verified in r4/r5:
// lane element j covers k = (l>>4)*8 + j; col = l&15; C row = any (A rows
// identical), use reg 0.
// ---------------------------------------------------------------------------
__global__ __launch_bounds__(512, 2) void ltc_main(
    const float* __restrict__ xp, const float* __restrict__ W,
    const float* __restrict__ tau, const float* __restrict__ A,
    const float* __restrict__ Wo, const float* __restrict__ bo,
    float* __restrict__ out)
{
  const int b  = blockIdx.x;
  const int t  = threadIdx.x;
  const int wv = t >> 6;       // 0..7
  const int l  = t & 63;
  const int g  = l >> 4;       // k-slice group 0..3
  const int c  = l & 15;       // col within 16-group
  const int s  = l >> 5;       // which col-group this lane keeps
  const int o  = wv * 32 + s * 16 + c;  // this lane's output (2 lanes/output)

  // B-fragments: 2 col-groups x 8 K-tiles, register-resident (64 VGPRs)
  f16x8 bw[2][8];
#pragma unroll
  for (int sg = 0; sg < 2; ++sg)
#pragma unroll
    for (int kt = 0; kt < 8; ++kt)
#pragma unroll
      for (int j = 0; j < 8; ++j)
        bw[sg][kt][j] =
            (_Float16)W[(I_ + kt * 32 + g * 8 + j) * H_ + (wv * 32 + sg * 16 + c)];

  __shared__ __align__(16) _Float16 hs[2][H_];
  __shared__ float hfin[H_];

  const float Aj   = A[o];
  const float itau = 1.0f / tau[o];
  const float dtA  = DT * Aj;
  const float base = 1.0f + DT * itau;

  const float* xprow = xp + (size_t)b * S_ * H_ + o;

  float h    = 0.0f;
  float xpre = xprow[0];
  if (t < H_) hs[0][t] = (_Float16)0.0f;
  __syncthreads();

#define LTC_BODY(RB, WB, STEP)                                               \
  {                                                                          \
    const _Float16* hb = &hs[RB][g * 8];                                     \
    f16x8 a[8];                                                              \
    _Pragma("unroll")                                                        \
    for (int kt = 0; kt < 8; ++kt) a[kt] = *(const f16x8*)(hb + kt * 32);    \
    const int snext = ((STEP) + 1 < S_) ? (STEP) + 1 : (STEP);               \
    const float xnext = xprow[(size_t)snext * H_];                           \
    f32x4 ac00 = {xpre, xpre, xpre, xpre};                                   \
    f32x4 ac01 = {0.f, 0.f, 0.f, 0.f};                                      \
    f32x4 ac10 = {xpre, xpre, xpre, xpre};                                   \
    f32x4 ac11 = {0.f, 0.f, 0.f, 0.f};                                      \
    __builtin_amdgcn_s_setprio(1);                                           \
    _Pragma("unroll")                                                        \
    for (int kt = 0; kt < 4; ++kt) {                                         \
      ac00 = __builtin_amdgcn_mfma_f32_16x16x32_f16(a[kt], bw[0][kt], ac00,  \
                                                    0, 0, 0);                \
      ac10 = __builtin_amdgcn_mfma_f32_16x16x32_f16(a[kt], bw[1][kt], ac10,  \
                                                    0, 0, 0);                \
      ac01 = __builtin_amdgcn_mfma_f32_16x16x32_f16(a[kt + 4], bw[0][kt + 4],\
                                                    ac01, 0, 0, 0);          \
      ac11 = __builtin_amdgcn_mfma_f32_16x16x32_f16(a[kt + 4], bw[1][kt + 4],\
                                                    ac11, 0, 0, 0);          \
    }                                                                        \
    __builtin_amdgcn_s_setprio(0);                                           \
    const float z0 = ac00[0] + ac01[0];                                      \
    const float z1 = ac10[0] + ac11[0];                                      \
    float z = (l & 32) ? z1 : z0;                                            \
    z = fminf(15.0f, fmaxf(-15.0f, z));                                      \
    const float E = __expf(2.0f * z);                                        \
    const float f = (E - 1.0f) * __builtin_amdgcn_rcpf(E + 1.0f);            \
    h = fmaf(dtA, f, h) * __builtin_amdgcn_rcpf(fmaf(DT, f, base));          \
    if (!(l & 16)) hs[WB][o] = (_Float16)h;                                  \
    xpre = xnext;                                                            \
    __syncthreads();                                                         \
  }

  for (int st = 0; st < S_; st += 2) {
    LTC_BODY(0, 1, st)
    LTC_BODY(1, 0, st + 1)
  }
#undef LTC_BODY

  // stage final f32 h, then fused output projection
  if (!(l & 16)) hfin[o] = h;
  __syncthreads();

  if (t < O_) {
    float accO = bo[t];
#pragma unroll 8
    for (int hh = 0; hh < H_; ++hh)
      accO = fmaf(hfin[hh], Wo[hh * O_ + t], accO);
    out[b * O_ + t] = accO;
  }
}

// ---------------------------------------------------------------------------
// Fallback (no workspace): proven structure with inline x-proj.
// ---------------------------------------------------------------------------
__global__ __launch_bounds__(1024) void ltc_inline(
    const float* __restrict__ x, const float* __restrict__ W,
    const float* __restrict__ bias, const float* __restrict__ tau,
    const float* __restrict__ A, const float* __restrict__ Wo,
    const float* __restrict__ bo, float* __restrict__ out)
{
  const int b = blockIdx.x;
  const int t = threadIdx.x;
  const int j = t & (H_ - 1);
  const int c = t >> 8;

  float wh[64], wx[32];
#pragma unroll
  for (int kk = 0; kk < 64; ++kk)
    wh[kk] = W[(I_ + c * 64 + kk) * H_ + j];
#pragma unroll
  for (int kk = 0; kk < 32; ++kk)
    wx[kk] = W[(c * 32 + kk) * H_ + j];

  __shared__ __align__(16) float hsf[H_];
  __shared__ __align__(16) float xsf[I_];
  __shared__ float ps[3][H_];

  float Aj = 0.f, itau = 0.f, bj = 0.f;
  if (c == 0) {
    Aj = A[j];
    itau = 1.0f / tau[j];
    bj = bias[j];
    hsf[j] = 0.0f;
  }
  const float4* xrow4 = (const float4*)(x + (size_t)b * S_ * I_);
  if (t < 32) ((float4*)xsf)[t] = xrow4[t];
  __syncthreads();

  for (int step = 0; step < S_; ++step) {
    float4 xnext4 = make_float4(0.f, 0.f, 0.f, 0.f);
    if (t < 32) {
      const int snext = (step + 1 < S_) ? step + 1 : step;
      xnext4 = xrow4[snext * 32 + t];
    }

    float acc = 0.0f;
#pragma unroll
    for (int kk = 0; kk < 64; kk += 4) {
      float4 h4 = *(const float4*)&hsf[c * 64 + kk];
      acc = fmaf(h4.x, wh[kk + 0], acc);
      acc = fmaf(h4.y, wh[kk + 1], acc);
      acc = fmaf(h4.z, wh[kk + 2], acc);
      acc = fmaf(h4.w, wh[kk + 3], acc);
    }
#pragma unroll
    for (int kk = 0; kk < 32; kk += 4) {
      float4 x4 = *(const float4*)&xsf[c * 32 + kk];
      acc = fmaf(x4.x, wx[kk + 0], acc);
      acc = fmaf(x4.y, wx[kk + 1], acc);
      acc = fmaf(x4.z, wx[kk + 2], acc);
      acc = fmaf(x4.w, wx[kk + 3], acc);
    }

    if (c) ps[c - 1][j] = acc;
    __syncthreads();

    if (t < 32) ((float4*)xsf)[t] = xnext4;
    if (c == 0) {
      const float z = acc + ps[0][j] + ps[1][j] + ps[2][j] + bj;
      const float f = tanhf(z);
      const float hj = hsf[j];
      hsf[j] = (hj + DT * f * Aj) / (1.0f + DT * (itau + f));
    }
    __syncthreads();
  }

  if (t < O_) {
    float acc = bo[t];
#pragma unroll 8
    for (int h = 0; h < H_; ++h)
      acc = fmaf(hsf[h], Wo[h * O_ + t], acc);
    out[b * O_ + t] = acc;
  }
}

// ---------------------------------------------------------------------------
extern "C" void kernel_launch(void* const* d_in, const int* in_sizes, int n_in,
                              void* d_out, int out_size, void* d_ws, size_t ws_size,
                              hipStream_t stream) {
  const float* x   = (const float*)d_in[0];
  const float* W   = (const float*)d_in[1];
  const float* b   = (const float*)d_in[2];
  const float* tau = (const float*)d_in[3];
  const float* A   = (const float*)d_in[4];
  const float* Wo  = (const float*)d_in[5];
  const float* bo  = (const float*)d_in[6];
  float* out = (float*)d_out;

  const size_t XP_BYTES = (size_t)B_ * S_ * H_ * sizeof(float);

  if (ws_size >= XP_BYTES) {
    float* xp = (float*)d_ws;
    hipLaunchKernelGGL(xproj_kernel, dim3((B_ * S_) / RPB), dim3(256), 0, stream,
                       x, W, b, xp);
    hipLaunchKernelGGL(ltc_main, dim3(B_), dim3(512), 0, stream,
                       xp, W, tau, A, Wo, bo, out);
  } else {
    hipLaunchKernelGGL(ltc_inline, dim3(B_), dim3(1024), 0, stream,
                       x, W, b, tau, A, Wo, bo, out);
  }
}